// Round 2
// baseline (941.803 us; speedup 1.0000x reference)
//
#include <hip/hip_runtime.h>
#include <hip/hip_bf16.h>
#include <cstdint>
#include <math.h>

// ============================================================================
// GCN 3-layer forward on MI355X.
// Strategy:
//  - Build dst-CSR once per launch (degree -> scan -> fill). Aggregation is a
//    deterministic per-node gather (no float atomics).
//  - Bias b1/b2 cancel exactly under PairNorm centering -> dropped.
//  - PairNorm stats (colsum, sum-of-squares) fused into AGG epilogue.
//  - PairNorm apply + ReLU fused into next GEMM's A-tile load.
//  - b3 + log_softmax fused into the final 40-wide AGG (wave-parallel).
//  - AGG edge loop: 64 CSR records fetched coalesced into LDS, broadcast-read,
//    unrolled x4 so 4 independent H-row gathers are in flight per wave.
// ============================================================================

// ---------------- degree count ----------------
__global__ void k_degree(const int* __restrict__ dst, int E, int* __restrict__ deg) {
    int e = blockIdx.x * 256 + threadIdx.x;
    if (e < E) atomicAdd(&deg[dst[e]], 1);
}

// ---------------- scan (chunk = 1024 per block) ----------------
__global__ void k_block_sums(const int* __restrict__ deg, int n, int* __restrict__ bsum) {
    __shared__ int sh[256];
    int base = blockIdx.x * 1024;
    int t = threadIdx.x;
    int s = 0;
#pragma unroll
    for (int j = 0; j < 4; ++j) {
        int idx = base + t + j * 256;
        if (idx < n) s += deg[idx];
    }
    sh[t] = s;
    __syncthreads();
    for (int off = 128; off > 0; off >>= 1) {
        if (t < off) sh[t] += sh[t + off];
        __syncthreads();
    }
    if (t == 0) bsum[blockIdx.x] = sh[0];
}

// exclusive scan of up to 256 block sums, single block of 256 threads
__global__ void k_scan_bsums(int* __restrict__ bs, int nb) {
    __shared__ int sh[256];
    int t = threadIdx.x;
    int v = (t < nb) ? bs[t] : 0;
    sh[t] = v;
    __syncthreads();
    for (int d = 1; d < 256; d <<= 1) {
        int y = (t >= d) ? sh[t - d] : 0;
        __syncthreads();
        sh[t] += y;
        __syncthreads();
    }
    if (t < nb) bs[t] = sh[t] - v;   // exclusive
}

// per-element exclusive offsets + inv-sqrt-degree
__global__ void k_offsets_isd(const int* __restrict__ deg, int n,
                              const int* __restrict__ boff, int* __restrict__ off,
                              float* __restrict__ isd) {
    int t = threadIdx.x;
    int base = blockIdx.x * 1024 + t * 4;
    int v[4];
#pragma unroll
    for (int j = 0; j < 4; ++j) {
        int idx = base + j;
        v[j] = (idx < n) ? deg[idx] : 0;
    }
    int tot = v[0] + v[1] + v[2] + v[3];
    int lane = t & 63, wid = t >> 6;
    int x = tot;
#pragma unroll
    for (int d = 1; d < 64; d <<= 1) {
        int y = __shfl_up(x, d, 64);
        if (lane >= d) x += y;
    }
    __shared__ int wsum[4];
    if (lane == 63) wsum[wid] = x;
    __syncthreads();
    int wbase = 0;
    for (int wdx = 0; wdx < wid; ++wdx) wbase += wsum[wdx];
    int b = boff[blockIdx.x] + wbase + (x - tot);
    int run = 0;
#pragma unroll
    for (int j = 0; j < 4; ++j) {
        int idx = base + j;
        if (idx < n) {
            off[idx] = b + run;
            isd[idx] = rsqrtf((float)(v[j] + 1));   // +1 self-loop; always >=1
        }
        run += v[j];
    }
}

// ---------------- CSR fill: record = {src, isd[src]*isd[dst]} ----------------
__global__ void k_fill(const int* __restrict__ src, const int* __restrict__ dst, int E,
                       const int* __restrict__ off, int* __restrict__ cur,
                       const float* __restrict__ isd, uint2* __restrict__ csr) {
    int e = blockIdx.x * 256 + threadIdx.x;
    if (e >= E) return;
    int s = src[e], d = dst[e];
    int pos = off[d] + atomicAdd(&cur[d], 1);
    csr[pos] = make_uint2((unsigned)s, __float_as_uint(isd[s] * isd[d]));
}

// ---------------- register-tiled fp32 GEMM ----------------
// C[M x BN] = A[M x K] * B[K x BN]; BN covers the full output width.
// TRANS: A-element transform y = relu((a - mu[k]) * alpha), stat = {mu[K], alpha}
template <int BM, int BN, int BK, int TM, int TN, bool TRANS>
__global__ __launch_bounds__(256) void k_gemm(const float* __restrict__ A,
                                              const float* __restrict__ B,
                                              float* __restrict__ C, int M, int K,
                                              const float* __restrict__ stat) {
    constexpr int TGN = BN / TN;
    __shared__ float As[BK][BM + 4];   // k-major (transposed in LDS)
    __shared__ float Bs[BK][BN + 4];
    const int tid = threadIdx.x;
    const int tmi = tid / TGN, tni = tid % TGN;
    const int row0 = blockIdx.x * BM;

    float alpha = 1.0f;
    if constexpr (TRANS) alpha = stat[K];

    float acc[TM][TN];
#pragma unroll
    for (int i = 0; i < TM; ++i)
#pragma unroll
        for (int j = 0; j < TN; ++j) acc[i][j] = 0.0f;

    for (int k0 = 0; k0 < K; k0 += BK) {
        constexpr int AF4 = BM * BK / 4;
#pragma unroll
        for (int i = tid; i < AF4; i += 256) {
            int r = i / (BK / 4);
            int kc = (i % (BK / 4)) * 4;
            int gr = row0 + r;
            float4 v = make_float4(0.f, 0.f, 0.f, 0.f);
            if (gr < M) v = *(const float4*)&A[(size_t)gr * K + k0 + kc];
            if constexpr (TRANS) {
                v.x = fmaxf((v.x - stat[k0 + kc + 0]) * alpha, 0.0f);
                v.y = fmaxf((v.y - stat[k0 + kc + 1]) * alpha, 0.0f);
                v.z = fmaxf((v.z - stat[k0 + kc + 2]) * alpha, 0.0f);
                v.w = fmaxf((v.w - stat[k0 + kc + 3]) * alpha, 0.0f);
            }
            As[kc + 0][r] = v.x;
            As[kc + 1][r] = v.y;
            As[kc + 2][r] = v.z;
            As[kc + 3][r] = v.w;
        }
        constexpr int BF4 = BK * BN / 4;
#pragma unroll
        for (int i = tid; i < BF4; i += 256) {
            int kk = i / (BN / 4);
            int nc = (i % (BN / 4)) * 4;
            float4 v = *(const float4*)&B[(size_t)(k0 + kk) * BN + nc];
            *(float4*)&Bs[kk][nc] = v;
        }
        __syncthreads();
#pragma unroll 8
        for (int kk = 0; kk < BK; ++kk) {
            float af[TM], bf[TN];
            const float* ap = &As[kk][tmi * TM];
            const float* bp = &Bs[kk][tni * TN];
#pragma unroll
            for (int i = 0; i < TM; ++i) af[i] = ap[i];
#pragma unroll
            for (int j = 0; j < TN; ++j) bf[j] = bp[j];
#pragma unroll
            for (int i = 0; i < TM; ++i)
#pragma unroll
                for (int j = 0; j < TN; ++j) acc[i][j] = fmaf(af[i], bf[j], acc[i][j]);
        }
        __syncthreads();
    }
#pragma unroll
    for (int i = 0; i < TM; ++i) {
        int gr = row0 + tmi * TM + i;
        if (gr < M) {
#pragma unroll
            for (int j = 0; j < TN; ++j) C[(size_t)gr * BN + tni * TN + j] = acc[i][j];
        }
    }
}

// ---------------- aggregation, F=128, fused PairNorm stats ----------------
// out[n] = isd[n]^2 * H[n] + sum_e coef_e * H[src_e];  stats: colsum[128], sumsq at [128]
__global__ __launch_bounds__(256) void k_agg128(const float* __restrict__ H,
                                                const uint2* __restrict__ csr,
                                                const int* __restrict__ off,
                                                const int* __restrict__ deg,
                                                const float* __restrict__ isd, int N,
                                                float* __restrict__ out,
                                                float* __restrict__ stats) {
    const int lane = threadIdx.x & 63;
    const int wid = threadIdx.x >> 6;
    const int gw = blockIdx.x * 4 + wid;
    const int nw = gridDim.x * 4;
    __shared__ uint2 recs[4][64];
    float csx = 0.f, csy = 0.f, ssq = 0.f;
    for (int n = gw; n < N; n += nw) {
        const float isdn = isd[n];
        const size_t rb = (size_t)n * 128 + lane * 2;
        float2 h0 = *(const float2*)&H[rb];
        float ax = h0.x * isdn * isdn;
        float ay = h0.y * isdn * isdn;
        const int e0 = off[n], dn = deg[n];
        for (int i0 = 0; i0 < dn; i0 += 64) {
            const int cnt = min(dn - i0, 64);
            if (lane < cnt) recs[wid][lane] = csr[e0 + i0 + lane];  // coalesced batch
            int j = 0;
            for (; j + 4 <= cnt; j += 4) {                          // 4 gathers in flight
                const uint2 c0 = recs[wid][j + 0];
                const uint2 c1 = recs[wid][j + 1];
                const uint2 c2 = recs[wid][j + 2];
                const uint2 c3 = recs[wid][j + 3];
                const float2 v0 = *(const float2*)&H[(size_t)c0.x * 128 + lane * 2];
                const float2 v1 = *(const float2*)&H[(size_t)c1.x * 128 + lane * 2];
                const float2 v2 = *(const float2*)&H[(size_t)c2.x * 128 + lane * 2];
                const float2 v3 = *(const float2*)&H[(size_t)c3.x * 128 + lane * 2];
                ax = fmaf(__uint_as_float(c0.y), v0.x, ax);
                ay = fmaf(__uint_as_float(c0.y), v0.y, ay);
                ax = fmaf(__uint_as_float(c1.y), v1.x, ax);
                ay = fmaf(__uint_as_float(c1.y), v1.y, ay);
                ax = fmaf(__uint_as_float(c2.y), v2.x, ax);
                ay = fmaf(__uint_as_float(c2.y), v2.y, ay);
                ax = fmaf(__uint_as_float(c3.y), v3.x, ax);
                ay = fmaf(__uint_as_float(c3.y), v3.y, ay);
            }
            for (; j < cnt; ++j) {
                const uint2 cu = recs[wid][j];
                const float c = __uint_as_float(cu.y);
                const float2 hv = *(const float2*)&H[(size_t)cu.x * 128 + lane * 2];
                ax = fmaf(c, hv.x, ax);
                ay = fmaf(c, hv.y, ay);
            }
        }
        *(float2*)&out[rb] = make_float2(ax, ay);
        csx += ax;
        csy += ay;
        ssq = fmaf(ax, ax, fmaf(ay, ay, ssq));
    }
    // block-level stats reduction, then one atomic flush per column per block
    __shared__ float2 scs[4][64];
    __shared__ float ssq_s[4];
    scs[wid][lane] = make_float2(csx, csy);
    float sq = ssq;
#pragma unroll
    for (int d = 32; d >= 1; d >>= 1) sq += __shfl_xor(sq, d, 64);
    if (lane == 0) ssq_s[wid] = sq;
    __syncthreads();
    if (wid == 0) {
        float2 t0 = scs[0][lane], t1 = scs[1][lane], t2 = scs[2][lane], t3 = scs[3][lane];
        float tx = t0.x + t1.x + t2.x + t3.x;
        float ty = t0.y + t1.y + t2.y + t3.y;
        atomicAdd(&stats[lane * 2 + 0], tx);
        atomicAdd(&stats[lane * 2 + 1], ty);
        if (lane == 0) atomicAdd(&stats[128], ssq_s[0] + ssq_s[1] + ssq_s[2] + ssq_s[3]);
    }
}

// ---------------- PairNorm finalize: mu[128], alpha at [128] ----------------
__global__ void k_finalize(const float* __restrict__ stats, float* __restrict__ mu_alpha,
                           float invN) {
    int t = threadIdx.x;   // 128 threads
    float mu = stats[t] * invN;
    mu_alpha[t] = mu;
    float v = mu * mu;
#pragma unroll
    for (int d = 32; d >= 1; d >>= 1) v += __shfl_xor(v, d, 64);
    __shared__ float s2[2];
    if ((t & 63) == 0) s2[t >> 6] = v;
    __syncthreads();
    if (t == 0) {
        float ms = stats[128] * invN - (s2[0] + s2[1]);
        mu_alpha[128] = rsqrtf(ms + 1e-6f);
    }
}

// ---------------- final aggregation F=40 + bias + log_softmax ----------------
__global__ __launch_bounds__(256) void k_agg_out(const float* __restrict__ H,
                                                 const uint2* __restrict__ csr,
                                                 const int* __restrict__ off,
                                                 const int* __restrict__ deg,
                                                 const float* __restrict__ isd, int N, int F,
                                                 const float* __restrict__ bias,
                                                 float* __restrict__ out) {
    const int lane = threadIdx.x & 63;
    const int wid = threadIdx.x >> 6;
    const int gw = blockIdx.x * 4 + wid;
    const int nw = gridDim.x * 4;
    __shared__ uint2 recs[4][64];
    const bool act = lane < F;
    const float bv = act ? bias[lane] : 0.0f;
    for (int n = gw; n < N; n += nw) {
        const float isdn = isd[n];
        float a = act ? H[(size_t)n * F + lane] * isdn * isdn : 0.0f;
        const int e0 = off[n], dn = deg[n];
        for (int i0 = 0; i0 < dn; i0 += 64) {
            const int cnt = min(dn - i0, 64);
            if (lane < cnt) recs[wid][lane] = csr[e0 + i0 + lane];
            int j = 0;
            for (; j + 4 <= cnt; j += 4) {
                const uint2 c0 = recs[wid][j + 0];
                const uint2 c1 = recs[wid][j + 1];
                const uint2 c2 = recs[wid][j + 2];
                const uint2 c3 = recs[wid][j + 3];
                const float v0 = act ? H[(size_t)c0.x * F + lane] : 0.0f;
                const float v1 = act ? H[(size_t)c1.x * F + lane] : 0.0f;
                const float v2 = act ? H[(size_t)c2.x * F + lane] : 0.0f;
                const float v3 = act ? H[(size_t)c3.x * F + lane] : 0.0f;
                a = fmaf(__uint_as_float(c0.y), v0, a);
                a = fmaf(__uint_as_float(c1.y), v1, a);
                a = fmaf(__uint_as_float(c2.y), v2, a);
                a = fmaf(__uint_as_float(c3.y), v3, a);
            }
            for (; j < cnt; ++j) {
                const uint2 cu = recs[wid][j];
                const float c = __uint_as_float(cu.y);
                const float hv = act ? H[(size_t)cu.x * F + lane] : 0.0f;
                a = fmaf(c, hv, a);
            }
        }
        a += bv;
        // wave-parallel log_softmax over F=40 active lanes
        float m = act ? a : -INFINITY;
#pragma unroll
        for (int d = 32; d >= 1; d >>= 1) m = fmaxf(m, __shfl_xor(m, d, 64));
        float ex = act ? __expf(a - m) : 0.0f;
        float s = ex;
#pragma unroll
        for (int d = 32; d >= 1; d >>= 1) s += __shfl_xor(s, d, 64);
        if (act) out[(size_t)n * F + lane] = a - m - __logf(s);
    }
}

// ============================================================================
extern "C" void kernel_launch(void* const* d_in, const int* in_sizes, int n_in,
                              void* d_out, int out_size, void* d_ws, size_t ws_size,
                              hipStream_t stream) {
    const float* x  = (const float*)d_in[0];
    const int*   ei = (const int*)d_in[1];      // int32 per harness contract
    const float* W1 = (const float*)d_in[2];
    const float* W2 = (const float*)d_in[4];
    const float* W3 = (const float*)d_in[6];
    const float* b3 = (const float*)d_in[7];
    // b1, b2 cancel exactly under PairNorm centering.

    const int HID = in_sizes[3];            // 128
    const int DIN = in_sizes[2] / HID;      // 256
    const int N   = in_sizes[0] / DIN;      // 100000
    const int E   = in_sizes[1] / 2;        // 1600000
    const int NC  = in_sizes[7];            // 40

    const int* esrc = ei;
    const int* edst = ei + E;

    // ---- workspace carve (256B aligned) ----
    char* w = (char*)d_ws;
    size_t o = 0;
    auto carve = [&](size_t bytes) -> void* {
        void* p = w + o;
        o = (o + bytes + 255) & ~(size_t)255;
        return p;
    };
    int*   deg  = (int*)carve((size_t)N * 4);
    int*   cur  = (int*)carve((size_t)N * 4);
    float* S1   = (float*)carve(129 * 4);
    float* S2   = (float*)carve(129 * 4);
    size_t zero_span = o;                         // deg, cur, S1, S2 need zeros
    int*   off  = (int*)carve((size_t)N * 4);
    float* isd  = (float*)carve((size_t)N * 4);
    float* M1   = (float*)carve(129 * 4);
    float* M2   = (float*)carve(129 * 4);
    int*   bsum = (int*)carve(1024 * 4);
    uint2* csr  = (uint2*)carve((size_t)E * 8);
    float* B0   = (float*)carve((size_t)N * HID * 4);
    float* B1   = (float*)carve((size_t)N * HID * 4);

    hipMemsetAsync(d_ws, 0, zero_span, stream);

    dim3 blk(256);
    const int nb = (N + 1023) / 1024;

    // ---- CSR construction ----
    k_degree<<<dim3((E + 255) / 256), blk, 0, stream>>>(edst, E, deg);
    k_block_sums<<<dim3(nb), blk, 0, stream>>>(deg, N, bsum);
    k_scan_bsums<<<dim3(1), blk, 0, stream>>>(bsum, nb);
    k_offsets_isd<<<dim3(nb), blk, 0, stream>>>(deg, N, bsum, off, isd);
    k_fill<<<dim3((E + 255) / 256), blk, 0, stream>>>(esrc, edst, E, off, cur, isd, csr);

    const int gemm_blocks = (N + 127) / 128;
    const int agg_blocks = 2048;

    // ---- layer 1 ----
    k_gemm<128, 128, 32, 8, 8, false><<<dim3(gemm_blocks), blk, 0, stream>>>(x, W1, B0, N, DIN, nullptr);
    k_agg128<<<dim3(agg_blocks), blk, 0, stream>>>(B0, csr, off, deg, isd, N, B1, S1);
    k_finalize<<<dim3(1), dim3(128), 0, stream>>>(S1, M1, 1.0f / (float)N);

    // ---- layer 2 ----
    k_gemm<128, 128, 32, 8, 8, true><<<dim3(gemm_blocks), blk, 0, stream>>>(B1, W2, B0, N, HID, M1);
    k_agg128<<<dim3(agg_blocks), blk, 0, stream>>>(B0, csr, off, deg, isd, N, B1, S2);
    k_finalize<<<dim3(1), dim3(128), 0, stream>>>(S2, M2, 1.0f / (float)N);

    // ---- layer 3 ----
    k_gemm<128, 40, 32, 4, 5, true><<<dim3(gemm_blocks), blk, 0, stream>>>(B1, W3, B0, N, HID, M2);
    k_agg_out<<<dim3(agg_blocks), blk, 0, stream>>>(B0, csr, off, deg, isd, N, NC, b3, (float*)d_out);
}

// Round 10
// 810.640 us; speedup vs baseline: 1.1618x; 1.1618x over previous
//
#include <hip/hip_runtime.h>
#include <hip/hip_bf16.h>
#include <hip/hip_fp16.h>
#include <cstdint>
#include <math.h>

// ============================================================================
// GCN 3-layer forward on MI355X.
//  - dst-CSR build once per launch; aggregation = deterministic gather.
//  - b1/b2 cancel under PairNorm centering -> dropped.
//  - PairNorm stats fused into AGG; PairNorm apply + ReLU fused into GEMM A-load.
//  - b3 + log_softmax fused into final 40-wide AGG.
//  - AGG input H in fp16 (halved gather bytes), fp32 accumulate.
//  - GEMM: v_mfma_f32_16x16x32_f16, fp32 accum. B pre-packed to fragment
//    order (coalesced, L2-resident). A/B k-permutation cancels in the
//    contraction; C/D mapping is the HW-verified col=lane&15 /
//    row=(lane>>4)*4+reg. No LDS.
// ============================================================================

typedef _Float16 f16x8 __attribute__((ext_vector_type(8)));
typedef float f32x4 __attribute__((ext_vector_type(4)));

// ---------------- degree count ----------------
__global__ void k_degree(const int* __restrict__ dst, int E, int* __restrict__ deg) {
    int e = blockIdx.x * 256 + threadIdx.x;
    if (e < E) atomicAdd(&deg[dst[e]], 1);
}

// ---------------- scan (chunk = 1024 per block) ----------------
__global__ void k_block_sums(const int* __restrict__ deg, int n, int* __restrict__ bsum) {
    __shared__ int sh[256];
    int base = blockIdx.x * 1024;
    int t = threadIdx.x;
    int s = 0;
#pragma unroll
    for (int j = 0; j < 4; ++j) {
        int idx = base + t + j * 256;
        if (idx < n) s += deg[idx];
    }
    sh[t] = s;
    __syncthreads();
    for (int off = 128; off > 0; off >>= 1) {
        if (t < off) sh[t] += sh[t + off];
        __syncthreads();
    }
    if (t == 0) bsum[blockIdx.x] = sh[0];
}

__global__ void k_scan_bsums(int* __restrict__ bs, int nb) {
    __shared__ int sh[256];
    int t = threadIdx.x;
    int v = (t < nb) ? bs[t] : 0;
    sh[t] = v;
    __syncthreads();
    for (int d = 1; d < 256; d <<= 1) {
        int y = (t >= d) ? sh[t - d] : 0;
        __syncthreads();
        sh[t] += y;
        __syncthreads();
    }
    if (t < nb) bs[t] = sh[t] - v;   // exclusive
}

// per-element exclusive offsets + inv-sqrt-degree
__global__ void k_offsets_isd(const int* __restrict__ deg, int n,
                              const int* __restrict__ boff, int* __restrict__ off,
                              float* __restrict__ isd) {
    int t = threadIdx.x;
    int base = blockIdx.x * 1024 + t * 4;
    int v[4];
#pragma unroll
    for (int j = 0; j < 4; ++j) {
        int idx = base + j;
        v[j] = (idx < n) ? deg[idx] : 0;
    }
    int tot = v[0] + v[1] + v[2] + v[3];
    int lane = t & 63, wid = t >> 6;
    int x = tot;
#pragma unroll
    for (int d = 1; d < 64; d <<= 1) {
        int y = __shfl_up(x, d, 64);
        if (lane >= d) x += y;
    }
    __shared__ int wsum[4];
    if (lane == 63) wsum[wid] = x;
    __syncthreads();
    int wbase = 0;
    for (int wdx = 0; wdx < wid; ++wdx) wbase += wsum[wdx];
    int b = boff[blockIdx.x] + wbase + (x - tot);
    int run = 0;
#pragma unroll
    for (int j = 0; j < 4; ++j) {
        int idx = base + j;
        if (idx < n) {
            off[idx] = b + run;
            isd[idx] = rsqrtf((float)(v[j] + 1));   // +1 self-loop
        }
        run += v[j];
    }
}

// ---------------- CSR fill: record = {src, isd[src]*isd[dst]} ----------------
__global__ void k_fill(const int* __restrict__ src, const int* __restrict__ dst, int E,
                       const int* __restrict__ off, int* __restrict__ cur,
                       const float* __restrict__ isd, uint2* __restrict__ csr) {
    int e = blockIdx.x * 256 + threadIdx.x;
    if (e >= E) return;
    int s = src[e], d = dst[e];
    int pos = off[d] + atomicAdd(&cur[d], 1);
    csr[pos] = make_uint2((unsigned)s, __float_as_uint(isd[s] * isd[d]));
}

// ---------------- pack W (K x N fp32 row-major) into MFMA B-fragment order ---
// out[((jt*KT + kt)*64 + lane)*8 + s] = W[kt*32 + (lane>>4)*8 + s][jt*16 + (lane&15)]
// cols >= N padded with 0.
__global__ void k_packB(const float* __restrict__ W, __half* __restrict__ out,
                        int K, int N, int NT) {
    int idx = blockIdx.x * 256 + threadIdx.x;
    int KT = K / 32;
    int total = NT * KT * 64 * 8;
    if (idx >= total) return;
    int s = idx & 7;
    int lane = (idx >> 3) & 63;
    int frag = idx >> 9;
    int kt = frag % KT;
    int jt = frag / KT;
    int k = kt * 32 + (lane >> 4) * 8 + s;
    int c = jt * 16 + (lane & 15);
    out[idx] = (c < N) ? __float2half_rn(W[(size_t)k * N + c]) : __float2half_rn(0.0f);
}

// ---------------- MFMA fp16 GEMM: C[M x NOUT] = A[M x K] * B ----------------
// A fp32 row-major; TRANS: a -> relu((a - mu[k]) * alpha), stat = {mu[K], alpha}
// Bp: packed fragments from k_packB. C written as __half row-major.
// Block = 256 thr = 4 waves; each wave owns 16 rows x NT 16-col tiles.
template <int K, int NT, int NOUT, bool TRANS>
__global__ __launch_bounds__(256) void k_gemm_mfma(const float* __restrict__ A,
                                                   const __half* __restrict__ Bp,
                                                   __half* __restrict__ C, int M,
                                                   const float* __restrict__ stat) {
    constexpr int KT = K / 32;
    const int tid = threadIdx.x;
    const int wid = tid >> 6, lane = tid & 63;
    const int row0 = blockIdx.x * 64 + wid * 16;   // wave's 16 output rows
    const int kg = lane >> 4;                      // k-group (0..3)
    int arow = row0 + (lane & 15);
    if (arow >= M) arow = M - 1;                   // clamp; stores guarded below
    const float* Arow = A + (size_t)arow * K;

    float alpha = 1.0f;
    if constexpr (TRANS) alpha = stat[K];

    const f32x4 zero = {0.f, 0.f, 0.f, 0.f};
    f32x4 acc[NT];
#pragma unroll
    for (int j = 0; j < NT; ++j) acc[j] = zero;

    const f16x8* __restrict__ Bfrag = reinterpret_cast<const f16x8*>(Bp);

#pragma unroll
    for (int kt = 0; kt < KT; ++kt) {
        const int kb = kt * 32 + kg * 8;
        float4 a0 = *(const float4*)&Arow[kb];
        float4 a1 = *(const float4*)&Arow[kb + 4];
        float av[8] = {a0.x, a0.y, a0.z, a0.w, a1.x, a1.y, a1.z, a1.w};
        f16x8 af;
#pragma unroll
        for (int s = 0; s < 8; ++s) {
            float v = av[s];
            if constexpr (TRANS) v = fmaxf((v - stat[kb + s]) * alpha, 0.0f);
            af[s] = (_Float16)v;
        }
#pragma unroll
        for (int j = 0; j < NT; ++j) {
            f16x8 bf = Bfrag[(j * KT + kt) * 64 + lane];
            acc[j] = __builtin_amdgcn_mfma_f32_16x16x32_f16(af, bf, acc[j], 0, 0, 0);
        }
    }
    // C/D mapping (HW-verified): col = lane&15, row = kg*4 + reg
    const int crow = row0 + kg * 4;
    const int ccol = lane & 15;
#pragma unroll
    for (int j = 0; j < NT; ++j) {
        int col = j * 16 + ccol;
        if (col < NOUT) {
#pragma unroll
            for (int r = 0; r < 4; ++r) {
                int row = crow + r;
                if (row < M) C[(size_t)row * NOUT + col] = __float2half_rn(acc[j][r]);
            }
        }
    }
}

// ---------------- aggregation, F=128 (fp16 H), fused PairNorm stats ----------
// out[n] = isd[n]^2 * H[n] + sum_e coef_e * H[src_e];  stats: colsum[128], sumsq at [128]
__global__ __launch_bounds__(256) void k_agg128(const __half* __restrict__ H,
                                                const uint2* __restrict__ csr,
                                                const int* __restrict__ off,
                                                const int* __restrict__ deg,
                                                const float* __restrict__ isd, int N,
                                                float* __restrict__ out,
                                                float* __restrict__ stats) {
    const int lane = threadIdx.x & 63;
    const int wid = threadIdx.x >> 6;
    const int nw = gridDim.x * 4;
    __shared__ uint2 recs[4][64];
    float csx = 0.f, csy = 0.f, ssq = 0.f;

    int n = blockIdx.x * 4 + wid;
    int e0 = 0, dn = 0;
    float isdn = 0.f;
    if (n < N) { e0 = off[n]; dn = deg[n]; isdn = isd[n]; }
    while (n < N) {
        // prefetch next node's descriptors (overlaps with this node's gathers)
        const int n2 = n + nw;
        int e0n = 0, dnn = 0;
        float isdn2 = 0.f;
        if (n2 < N) { e0n = off[n2]; dnn = deg[n2]; isdn2 = isd[n2]; }

        const size_t rb = (size_t)n * 128 + lane * 2;
        float2 h0 = __half22float2(*(const __half2*)&H[rb]);
        float ax = h0.x * isdn * isdn;
        float ay = h0.y * isdn * isdn;
        for (int i0 = 0; i0 < dn; i0 += 64) {
            const int cnt = min(dn - i0, 64);
            if (lane < cnt) recs[wid][lane] = csr[e0 + i0 + lane];  // coalesced batch
            int j = 0;
            for (; j + 8 <= cnt; j += 8) {                          // 8 gathers in flight
                uint2 c[8];
                float2 v[8];
#pragma unroll
                for (int u = 0; u < 8; ++u) c[u] = recs[wid][j + u];
#pragma unroll
                for (int u = 0; u < 8; ++u)
                    v[u] = __half22float2(*(const __half2*)&H[(size_t)c[u].x * 128 + lane * 2]);
#pragma unroll
                for (int u = 0; u < 8; ++u) {
                    const float cf = __uint_as_float(c[u].y);
                    ax = fmaf(cf, v[u].x, ax);
                    ay = fmaf(cf, v[u].y, ay);
                }
            }
            for (; j < cnt; ++j) {
                const uint2 cu = recs[wid][j];
                const float cf = __uint_as_float(cu.y);
                const float2 hv = __half22float2(*(const __half2*)&H[(size_t)cu.x * 128 + lane * 2]);
                ax = fmaf(cf, hv.x, ax);
                ay = fmaf(cf, hv.y, ay);
            }
        }
        *(float2*)&out[rb] = make_float2(ax, ay);
        csx += ax;
        csy += ay;
        ssq = fmaf(ax, ax, fmaf(ay, ay, ssq));

        n = n2; e0 = e0n; dn = dnn; isdn = isdn2;
    }
    // block-level stats reduction, one atomic flush per column per block
    __shared__ float2 scs[4][64];
    __shared__ float ssq_s[4];
    scs[wid][lane] = make_float2(csx, csy);
    float sq = ssq;
#pragma unroll
    for (int d = 32; d >= 1; d >>= 1) sq += __shfl_xor(sq, d, 64);
    if (lane == 0) ssq_s[wid] = sq;
    __syncthreads();
    if (wid == 0) {
        float2 t0 = scs[0][lane], t1 = scs[1][lane], t2 = scs[2][lane], t3 = scs[3][lane];
        float tx = t0.x + t1.x + t2.x + t3.x;
        float ty = t0.y + t1.y + t2.y + t3.y;
        atomicAdd(&stats[lane * 2 + 0], tx);
        atomicAdd(&stats[lane * 2 + 1], ty);
        if (lane == 0) atomicAdd(&stats[128], ssq_s[0] + ssq_s[1] + ssq_s[2] + ssq_s[3]);
    }
}

// ---------------- PairNorm finalize: mu[128], alpha at [128] ----------------
__global__ void k_finalize(const float* __restrict__ stats, float* __restrict__ mu_alpha,
                           float invN) {
    int t = threadIdx.x;   // 128 threads
    float mu = stats[t] * invN;
    mu_alpha[t] = mu;
    float v = mu * mu;
#pragma unroll
    for (int d = 32; d >= 1; d >>= 1) v += __shfl_xor(v, d, 64);
    __shared__ float s2[2];
    if ((t & 63) == 0) s2[t >> 6] = v;
    __syncthreads();
    if (t == 0) {
        float ms = stats[128] * invN - (s2[0] + s2[1]);
        mu_alpha[128] = rsqrtf(ms + 1e-6f);
    }
}

// ---------------- final aggregation F=40 (fp16 H) + bias + log_softmax ------
__global__ __launch_bounds__(256) void k_agg_out(const __half* __restrict__ H,
                                                 const uint2* __restrict__ csr,
                                                 const int* __restrict__ off,
                                                 const int* __restrict__ deg,
                                                 const float* __restrict__ isd, int N, int F,
                                                 const float* __restrict__ bias,
                                                 float* __restrict__ out) {
    const int lane = threadIdx.x & 63;
    const int wid = threadIdx.x >> 6;
    const int nw = gridDim.x * 4;
    __shared__ uint2 recs[4][64];
    const bool act = lane < F;
    const float bv = act ? bias[lane] : 0.0f;

    int n = blockIdx.x * 4 + wid;
    int e0 = 0, dn = 0;
    float isdn = 0.f;
    if (n < N) { e0 = off[n]; dn = deg[n]; isdn = isd[n]; }
    while (n < N) {
        const int n2 = n + nw;
        int e0n = 0, dnn = 0;
        float isdn2 = 0.f;
        if (n2 < N) { e0n = off[n2]; dnn = deg[n2]; isdn2 = isd[n2]; }

        float a = act ? __half2float(H[(size_t)n * F + lane]) * isdn * isdn : 0.0f;
        for (int i0 = 0; i0 < dn; i0 += 64) {
            const int cnt = min(dn - i0, 64);
            if (lane < cnt) recs[wid][lane] = csr[e0 + i0 + lane];
            int j = 0;
            for (; j + 8 <= cnt; j += 8) {
                uint2 c[8];
                float v[8];
#pragma unroll
                for (int u = 0; u < 8; ++u) c[u] = recs[wid][j + u];
#pragma unroll
                for (int u = 0; u < 8; ++u)
                    v[u] = act ? __half2float(H[(size_t)c[u].x * F + lane]) : 0.0f;
#pragma unroll
                for (int u = 0; u < 8; ++u) a = fmaf(__uint_as_float(c[u].y), v[u], a);
            }
            for (; j < cnt; ++j) {
                const uint2 cu = recs[wid][j];
                const float hv = act ? __half2float(H[(size_t)cu.x * F + lane]) : 0.0f;
                a = fmaf(__uint_as_float(cu.y), hv, a);
            }
        }
        a += bv;
        // wave-parallel log_softmax over F=40 active lanes
        float m = act ? a : -INFINITY;
#pragma unroll
        for (int d = 32; d >= 1; d >>= 1) m = fmaxf(m, __shfl_xor(m, d, 64));
        float ex = act ? __expf(a - m) : 0.0f;
        float s = ex;
#pragma unroll
        for (int d = 32; d >= 1; d >>= 1) s += __shfl_xor(s, d, 64);
        if (act) out[(size_t)n * F + lane] = a - m - __logf(s);

        n = n2; e0 = e0n; dn = dnn; isdn = isdn2;
    }
}

// ============================================================================
extern "C" void kernel_launch(void* const* d_in, const int* in_sizes, int n_in,
                              void* d_out, int out_size, void* d_ws, size_t ws_size,
                              hipStream_t stream) {
    const float* x  = (const float*)d_in[0];
    const int*   ei = (const int*)d_in[1];      // int32 per harness contract (verified r2)
    const float* W1 = (const float*)d_in[2];
    const float* W2 = (const float*)d_in[4];
    const float* W3 = (const float*)d_in[6];
    const float* b3 = (const float*)d_in[7];
    // b1, b2 cancel exactly under PairNorm centering.

    const int HID = in_sizes[3];            // 128
    const int DIN = in_sizes[2] / HID;      // 256
    const int N   = in_sizes[0] / DIN;      // 100000
    const int E   = in_sizes[1] / 2;        // 1600000
    const int NC  = in_sizes[7];            // 40

    const int* esrc = ei;
    const int* edst = ei + E;

    // ---- workspace carve (256B aligned) ----
    char* w = (char*)d_ws;
    size_t o = 0;
    auto carve = [&](size_t bytes) -> void* {
        void* p = w + o;
        o = (o + bytes + 255) & ~(size_t)255;
        return p;
    };
    int*    deg  = (int*)carve((size_t)N * 4);
    int*    cur  = (int*)carve((size_t)N * 4);
    float*  S1   = (float*)carve(129 * 4);
    float*  S2   = (float*)carve(129 * 4);
    size_t zero_span = o;                         // deg, cur, S1, S2 need zeros
    int*    off  = (int*)carve((size_t)N * 4);
    float*  isd  = (float*)carve((size_t)N * 4);
    float*  M1   = (float*)carve(129 * 4);
    float*  M2   = (float*)carve(129 * 4);
    int*    bsum = (int*)carve(1024 * 4);
    uint2*  csr  = (uint2*)carve((size_t)E * 8);
    __half* B0h  = (__half*)carve((size_t)N * HID * 2);   // fp16 GEMM outputs
    float*  B1   = (float*)carve((size_t)N * HID * 4);    // fp32 agg outputs
    __half* Bp1  = (__half*)carve((size_t)8 * 8 * 64 * 8 * 2);   // 256x128 packed
    __half* Bp2  = (__half*)carve((size_t)8 * 4 * 64 * 8 * 2);   // 128x128 packed
    __half* Bp3  = (__half*)carve((size_t)3 * 4 * 64 * 8 * 2);   // 128x40 -> 3 tiles

    hipMemsetAsync(d_ws, 0, zero_span, stream);

    dim3 blk(256);
    const int nb = (N + 1023) / 1024;

    // ---- weight packing (fragment order, fp16) ----
    k_packB<<<dim3((8 * 8 * 512 + 255) / 256), blk, 0, stream>>>(W1, Bp1, DIN, HID, 8);
    k_packB<<<dim3((8 * 4 * 512 + 255) / 256), blk, 0, stream>>>(W2, Bp2, HID, HID, 8);
    k_packB<<<dim3((3 * 4 * 512 + 255) / 256), blk, 0, stream>>>(W3, Bp3, HID, NC, 3);

    // ---- CSR construction ----
    k_degree<<<dim3((E + 255) / 256), blk, 0, stream>>>(edst, E, deg);
    k_block_sums<<<dim3(nb), blk, 0, stream>>>(deg, N, bsum);
    k_scan_bsums<<<dim3(1), blk, 0, stream>>>(bsum, nb);
    k_offsets_isd<<<dim3(nb), blk, 0, stream>>>(deg, N, bsum, off, isd);
    k_fill<<<dim3((E + 255) / 256), blk, 0, stream>>>(esrc, edst, E, off, cur, isd, csr);

    const int gemm_blocks = (N + 63) / 64;
    const int agg_blocks = 2048;

    // ---- layer 1 ----
    k_gemm_mfma<256, 8, 128, false><<<dim3(gemm_blocks), blk, 0, stream>>>(x, Bp1, B0h, N, nullptr);
    k_agg128<<<dim3(agg_blocks), blk, 0, stream>>>(B0h, csr, off, deg, isd, N, B1, S1);
    k_finalize<<<dim3(1), dim3(128), 0, stream>>>(S1, M1, 1.0f / (float)N);

    // ---- layer 2 ----
    k_gemm_mfma<128, 8, 128, true><<<dim3(gemm_blocks), blk, 0, stream>>>(B1, Bp2, B0h, N, M1);
    k_agg128<<<dim3(agg_blocks), blk, 0, stream>>>(B0h, csr, off, deg, isd, N, B1, S2);
    k_finalize<<<dim3(1), dim3(128), 0, stream>>>(S2, M2, 1.0f / (float)N);

    // ---- layer 3 ----
    k_gemm_mfma<128, 3, 40, true><<<dim3(gemm_blocks), blk, 0, stream>>>(B1, Bp3, B0h, N, M2);
    k_agg_out<<<dim3(agg_blocks), blk, 0, stream>>>(B0h, csr, off, deg, isd, N, NC, b3, (float*)d_out);
}